// Round 4
// baseline (331.948 us; speedup 1.0000x reference)
//
#include <hip/hip_runtime.h>
#include <hip/hip_bf16.h>
#include <cstdint>

typedef __bf16 bf16_t;
typedef bf16_t bf16x8 __attribute__((ext_vector_type(8)));
typedef float  f32x4  __attribute__((ext_vector_type(4)));
typedef float  f32x2  __attribute__((ext_vector_type(2)));
typedef unsigned int u32;
typedef u32 u32x4 __attribute__((ext_vector_type(4)));
typedef u32 u32x2 __attribute__((ext_vector_type(2)));

#define S0 512
#define S1 256
#define S2 128
#define GPTS 16384

// workspace layout (bytes)
#define WS_BASE 0u
#define WS_W1P  32768u                          // 4 MB
#define WS_W2P  (32768u + 4194304u)             // 1 MB
#define WS_W3P  (32768u + 4194304u + 1048576u)  // 64 KB
#define WS_OLD_END (32768u + 4194304u + 1048576u + 65536u)
#define WS_W0BX WS_OLD_END                      // 32 KB (optional)
#define WS_W0BY (WS_OLD_END + 32768u)           // 32 KB (optional)
#define WS_NEED (WS_OLD_END + 65536u)

__device__ __forceinline__ u32 pkcvt(float lo, float hi) {
  __hip_bfloat162 h = __float22bfloat162_rn(make_float2(lo, hi));
  u32 u;
  __builtin_memcpy(&u, &h, 4);   // __hip_bfloat162 isn't trivially copyable -> no bit_cast
  return u;
}
__device__ __forceinline__ float tanh_fast(float x) {
  float e = __builtin_amdgcn_exp2f(x * 2.88539008f);   // 2*log2(e)
  return fmaf(-2.0f, __builtin_amdgcn_rcpf(e + 1.0f), 1.0f);
}
// XOR-swizzled LDS addressing: 16B-chunk ^= (row & 7). Bank-spread for both
// the b128 k-chunk reads and the b64 column-tile writes; no padding needed.
__device__ __forceinline__ int swzA(int row, int col) {  // [64][256]
  int ch = col >> 3;
  ch = (ch & ~7) | ((ch ^ row) & 7);
  return (row << 8) + (ch << 3) + (col & 7);
}
__device__ __forceinline__ int swzH(int row, int col) {  // [64][128]
  int ch = col >> 3;
  ch = (ch & ~7) | ((ch ^ row) & 7);
  return (row << 7) + (ch << 3) + (col & 7);
}

// ---------------------------------------------------------------------------
// prep: [0,2048)  base[m][o] = W0a·x0 + b0a + b0b (fp32)
//       [2048,2064)  deinterleave W0b -> W0bx/W0by (if ws has room)
//       [2064,3088)  W1 pack: wave per row, coalesced reads, frag stores
//       [3088,3600)  W2 pack: wave per row
//       [3600,3616)  W3 pack (N padded 3->16 with zeros)
// frag order [m][ks][nt][lane][8]: lane(quad,lrow) holds W[k=ks*32+quad*8+j][n=nt*16+lrow]
// ---------------------------------------------------------------------------
__global__ __launch_bounds__(256) void prep_k(
    const float* __restrict__ x0, const float* __restrict__ W0a,
    const float* __restrict__ b0a, const float* __restrict__ b0b,
    const float* __restrict__ W0b,
    const float* __restrict__ W1, const float* __restrict__ W2,
    const float* __restrict__ W3, float* __restrict__ base,
    bf16_t* __restrict__ W1p, bf16_t* __restrict__ W2p, bf16_t* __restrict__ W3p,
    float* __restrict__ W0bx, float* __restrict__ W0by, int deint)
{
  const int bid = blockIdx.x, tid = threadIdx.x;
  const int w = tid >> 6, L = tid & 63;
  if (bid < 2048) {
    int wid = (bid << 2) + w;
    int m = wid >> 9, o = wid & 511;
    const float* wrow = W0a + ((size_t)(m*S0 + o) << 10);
    float acc = 0.f;
#pragma unroll
    for (int i = 0; i < 4; ++i) {
      f32x4 wv = *(const f32x4*)(wrow + i*256 + L*4);
      f32x4 xv = *(const f32x4*)(x0   + i*256 + L*4);
      acc += wv.x*xv.x + wv.y*xv.y + wv.z*xv.z + wv.w*xv.w;
    }
#pragma unroll
    for (int s = 32; s; s >>= 1) acc += __shfl_xor(acc, s, 64);
    if (L == 0) base[m*S0 + o] = acc + b0a[m*S0 + o] + b0b[m*S0 + o];
  } else if (bid < 2064) {
    if (!deint) return;
    int T = (bid - 2048)*256 + tid;         // [0,4096)
    int m = T >> 8, p = (T & 255) << 1;     // pair index
    f32x4 v = *(const f32x4*)(W0b + ((size_t)m*S0 + p)*2);
    *(f32x2*)(W0bx + m*S0 + p) = (f32x2){v.x, v.z};
    *(f32x2*)(W0by + m*S0 + p) = (f32x2){v.y, v.w};
  } else if (bid < 3088) {
    int wid = (bid - 2064)*4 + w;           // [0,4096)
    int m = wid >> 8, n = wid & 255;
    const float* src = W1 + ((size_t)(m*S1 + n) << 9) + L*8;
    f32x4 a = *(const f32x4*)src;
    f32x4 b = *(const f32x4*)(src + 4);
    u32x4 pu;
    pu[0] = pkcvt(a.x, a.y); pu[1] = pkcvt(a.z, a.w);
    pu[2] = pkcvt(b.x, b.y); pu[3] = pkcvt(b.z, b.w);
    int ks = L >> 2, quad = L & 3, nt = n >> 4, lrow = n & 15;
    *(u32x4*)(W1p + (((size_t)(m*16 + ks)*16 + nt)*64 + quad*16 + lrow)*8) = pu;
  } else if (bid < 3600) {
    int wid = (bid - 3088)*4 + w;           // [0,2048)
    int m = wid >> 7, n = wid & 127;
    const float* src = W2 + ((size_t)(m*S2 + n) << 8) + L*4;
    f32x4 a = *(const f32x4*)src;
    u32x2 pu; pu[0] = pkcvt(a.x, a.y); pu[1] = pkcvt(a.z, a.w);
    int ks = L >> 3, quad = (L >> 1) & 3, half = L & 1, nt = n >> 4, lrow = n & 15;
    *(u32x2*)(W2p + (((size_t)(m*8 + ks)*8 + nt)*64 + quad*16 + lrow)*8 + half*4) = pu;
  } else {
    int T3 = (bid - 3600)*256 + tid;        // [0,4096)
    int l = T3 & 63, ks = (T3 >> 6) & 3, m = T3 >> 8;
    int n = l & 15, k0 = ks*32 + ((l >> 4) & 3)*8;
    bf16x8 v;
    if (n < 3) {
      const float* src = W3 + (size_t)(m*3 + n)*S2 + k0;
      f32x4 a = *(const f32x4*)src;
      f32x4 b = *(const f32x4*)(src + 4);
      v[0]=(bf16_t)a.x; v[1]=(bf16_t)a.y; v[2]=(bf16_t)a.z; v[3]=(bf16_t)a.w;
      v[4]=(bf16_t)b.x; v[5]=(bf16_t)b.y; v[6]=(bf16_t)b.z; v[7]=(bf16_t)b.w;
    } else {
#pragma unroll
      for (int j = 0; j < 8; ++j) v[j] = (bf16_t)0.f;
    }
    *(bf16x8*)(W3p + (size_t)T3*8) = v;
  }
}

// ---------------------------------------------------------------------------
// Fused MLP. One WG = (m = bid>>8, 64-row grid tile). Register h0-gen with
// packed f32 ops (v_pk_fma/v_pk_max + v_cvt_pk_bf16_f32). Swapped MFMA
// operands -> D = C^T (column-contiguous per thread). XOR-swizzled LDS,
// 32 KB -> 4 WG/CU.
// ---------------------------------------------------------------------------
__global__ __launch_bounds__(256, 4) void fused_mlp_k(
    const float* __restrict__ base, const float* __restrict__ W0b,
    const float* __restrict__ wxa, const float* __restrict__ wya, int deint,
    const bf16_t* __restrict__ W1p, const bf16_t* __restrict__ W2p,
    const bf16_t* __restrict__ W3p,
    const float* __restrict__ b1, const float* __restrict__ b2,
    const float* __restrict__ b3, float* __restrict__ out)
{
  __shared__ __align__(16) bf16_t sA1[64*256];  // 32 KB; reused as h2 [64][128]

  const int bid  = blockIdx.x;
  const int m    = bid >> 8;
  const int tile = bid & 255;
  const int g0   = tile * 64;

  const int tid  = threadIdx.x;
  const int w    = tid >> 6, L = tid & 63;
  const int quad = L >> 4, lrow = L & 15;

  const float step = 2.0f / 127.0f;
  const float yv  = -1.0f + (float)(tile >> 1) * step;
  const float xv0 = -1.0f + (float)(((tile & 1) << 6) + lrow) * step;

  const float* basep = base + m*S0;
  const float* w0bp  = W0b + (size_t)m*S0*2;
  const float* wxp   = wxa + m*S0;
  const float* wyp   = wya + m*S0;

  const f32x4 zero4 = {0.f, 0.f, 0.f, 0.f};
  f32x4 acc1[4][4];
#pragma unroll
  for (int a = 0; a < 4; ++a)
#pragma unroll
    for (int b = 0; b < 4; ++b) acc1[a][b] = zero4;

  // ---------------- Layer 1: K=512, 16 chunks, barrier-free ----------------
  const bf16_t* bp1 = W1p + (((size_t)(m*16)*16 + w*4)*64 + L)*8;
  const f32x4 yv4 = {yv, yv, yv, yv};

#pragma unroll 2
  for (int ks = 0; ks < 16; ++ks) {
    const int kk = ks*32 + quad*8;
    bf16x8 Bf[4];
    const bf16_t* bp = bp1 + (size_t)ks*8192;
#pragma unroll
    for (int n = 0; n < 4; ++n) Bf[n] = *(const bf16x8*)(bp + n*512);

    f32x4 c0 = *(const f32x4*)(basep + kk);
    f32x4 c1 = *(const f32x4*)(basep + kk + 4);
    f32x4 wx0v, wx1v, wy0v, wy1v;
    if (deint) {
      wx0v = *(const f32x4*)(wxp + kk); wx1v = *(const f32x4*)(wxp + kk + 4);
      wy0v = *(const f32x4*)(wyp + kk); wy1v = *(const f32x4*)(wyp + kk + 4);
    } else {
      f32x4 a = *(const f32x4*)(w0bp + kk*2);
      f32x4 b = *(const f32x4*)(w0bp + kk*2 + 4);
      f32x4 c = *(const f32x4*)(w0bp + kk*2 + 8);
      f32x4 d = *(const f32x4*)(w0bp + kk*2 + 12);
      wx0v = (f32x4){a.x, a.z, b.x, b.z}; wy0v = (f32x4){a.y, a.w, b.y, b.w};
      wx1v = (f32x4){c.x, c.z, d.x, d.z}; wy1v = (f32x4){c.y, c.w, d.y, d.w};
    }
    f32x4 t0 = __builtin_elementwise_fma(wy0v, yv4, c0);
    f32x4 t1 = __builtin_elementwise_fma(wy1v, yv4, c1);

#pragma unroll
    for (int mt = 0; mt < 4; ++mt) {
      const float xr = xv0 + (float)(mt*16)*step;
      const f32x4 xr4 = {xr, xr, xr, xr};
      f32x4 h0 = __builtin_elementwise_max(__builtin_elementwise_fma(wx0v, xr4, t0), zero4);
      f32x4 h1 = __builtin_elementwise_max(__builtin_elementwise_fma(wx1v, xr4, t1), zero4);
      u32x4 au;
      au[0] = pkcvt(h0.x, h0.y); au[1] = pkcvt(h0.z, h0.w);
      au[2] = pkcvt(h1.x, h1.y); au[3] = pkcvt(h1.z, h1.w);
      bf16x8 af;
      __builtin_memcpy(&af, &au, 16);
#pragma unroll
      for (int n = 0; n < 4; ++n)
        acc1[mt][n] = __builtin_amdgcn_mfma_f32_16x16x32_bf16(Bf[n], af, acc1[mt][n], 0, 0, 0);
    }
  }

  // L1 epilogue: +b1, relu, pk-cvt -> swizzled sA1
#pragma unroll
  for (int nb = 0; nb < 4; ++nb) {
    const int col = w*64 + nb*16 + quad*4;
    f32x4 bb = *(const f32x4*)(b1 + m*S1 + col);
#pragma unroll
    for (int mt = 0; mt < 4; ++mt) {
      const int row = mt*16 + lrow;
      f32x4 v = __builtin_elementwise_max(acc1[mt][nb] + bb, zero4);
      u32x2 s; s[0] = pkcvt(v.x, v.y); s[1] = pkcvt(v.z, v.w);
      *(u32x2*)(&sA1[swzA(row, col)]) = s;
    }
  }
  __syncthreads();

  // ---------------- Layer 2: K=256, 8 chunks ----------------
  f32x4 acc2[4][2];
#pragma unroll
  for (int a = 0; a < 4; ++a) { acc2[a][0] = zero4; acc2[a][1] = zero4; }
  const bf16_t* bp2 = W2p + (((size_t)(m*8)*8 + w*2)*64 + L)*8;
#pragma unroll 2
  for (int ks = 0; ks < 8; ++ks) {
    const int k2 = ks*32 + quad*8;
    bf16x8 af[4];
#pragma unroll
    for (int mt = 0; mt < 4; ++mt)
      af[mt] = *(const bf16x8*)(&sA1[swzA(mt*16 + lrow, k2)]);
    bf16x8 b0f = *(const bf16x8*)(bp2 + (size_t)ks*4096);
    bf16x8 b1f = *(const bf16x8*)(bp2 + (size_t)ks*4096 + 512);
#pragma unroll
    for (int mt = 0; mt < 4; ++mt)
      acc2[mt][0] = __builtin_amdgcn_mfma_f32_16x16x32_bf16(b0f, af[mt], acc2[mt][0], 0, 0, 0);
#pragma unroll
    for (int mt = 0; mt < 4; ++mt)
      acc2[mt][1] = __builtin_amdgcn_mfma_f32_16x16x32_bf16(b1f, af[mt], acc2[mt][1], 0, 0, 0);
  }
  __syncthreads();   // all sA1 reads done before aliased h2 writes

  // L2 epilogue: +b2, relu -> swizzled sH2 [64][128]
  bf16_t* sH2 = sA1;
#pragma unroll
  for (int nb = 0; nb < 2; ++nb) {
    const int col = w*32 + nb*16 + quad*4;
    f32x4 bb = *(const f32x4*)(b2 + m*S2 + col);
#pragma unroll
    for (int mt = 0; mt < 4; ++mt) {
      const int row = mt*16 + lrow;
      f32x4 v = __builtin_elementwise_max(acc2[mt][nb] + bb, zero4);
      u32x2 s; s[0] = pkcvt(v.x, v.y); s[1] = pkcvt(v.z, v.w);
      *(u32x2*)(&sH2[swzH(row, col)]) = s;
    }
  }
  __syncthreads();

  // ---------------- Layer 3: K=128, N padded to 16 ----------------
  f32x4 acc3 = zero4;
#pragma unroll
  for (int ks = 0; ks < 4; ++ks) {
    bf16x8 af  = *(const bf16x8*)(&sH2[swzH(w*16 + lrow, ks*32 + quad*8)]);
    bf16x8 bfr = *(const bf16x8*)(W3p + (((size_t)m*4 + ks)*64 + L)*8);
    acc3 = __builtin_amdgcn_mfma_f32_16x16x32_bf16(bfr, af, acc3, 0, 0, 0);
  }
  if (quad == 0) {
    const size_t o = ((size_t)m*GPTS + g0 + w*16 + lrow)*3;
    out[o + 0] = tanh_fast(acc3[0] + b3[m*3 + 0]);
    out[o + 1] = tanh_fast(acc3[1] + b3[m*3 + 1]);
    out[o + 2] = tanh_fast(acc3[2] + b3[m*3 + 2]);
  }
}

// ---------------------------------------------------------------------------
extern "C" void kernel_launch(void* const* d_in, const int* in_sizes, int n_in,
                              void* d_out, int out_size, void* d_ws, size_t ws_size,
                              hipStream_t stream) {
  const float* x0  = (const float*)d_in[0];
  const float* W0a = (const float*)d_in[1];
  const float* b0a = (const float*)d_in[2];
  const float* W0b = (const float*)d_in[3];
  const float* b0b = (const float*)d_in[4];
  const float* W1  = (const float*)d_in[5];
  const float* b1  = (const float*)d_in[6];
  const float* W2  = (const float*)d_in[7];
  const float* b2  = (const float*)d_in[8];
  const float* W3  = (const float*)d_in[9];
  const float* b3  = (const float*)d_in[10];

  char* ws = (char*)d_ws;
  float*  base = (float*)(ws + WS_BASE);
  bf16_t* W1p  = (bf16_t*)(ws + WS_W1P);
  bf16_t* W2p  = (bf16_t*)(ws + WS_W2P);
  bf16_t* W3p  = (bf16_t*)(ws + WS_W3P);
  float*  W0bx = (float*)(ws + WS_W0BX);
  float*  W0by = (float*)(ws + WS_W0BY);
  float*  out  = (float*)d_out;
  int deint = (ws_size >= (size_t)WS_NEED) ? 1 : 0;

  prep_k<<<3616, 256, 0, stream>>>(x0, W0a, b0a, b0b, W0b, W1, W2, W3,
                                   base, W1p, W2p, W3p, W0bx, W0by, deint);
  fused_mlp_k<<<4096, 256, 0, stream>>>(base, W0b, W0bx, W0by, deint,
                                        W1p, W2p, W3p, b1, b2, b3, out);
}

// Round 5
// 232.124 us; speedup vs baseline: 1.4300x; 1.4300x over previous
//
#include <hip/hip_runtime.h>
#include <hip/hip_bf16.h>
#include <cstdint>

typedef __bf16 bf16_t;
typedef bf16_t bf16x8 __attribute__((ext_vector_type(8)));
typedef float  f32x4  __attribute__((ext_vector_type(4)));
typedef float  f32x2  __attribute__((ext_vector_type(2)));
typedef unsigned int u32;
typedef u32 u32x4 __attribute__((ext_vector_type(4)));
typedef u32 u32x2 __attribute__((ext_vector_type(2)));

#define S0 512
#define S1 256
#define S2 128
#define GPTS 16384

// workspace layout (bytes)
#define WS_BASE 0u
#define WS_W1P  32768u                          // 4 MB
#define WS_W2P  (32768u + 4194304u)             // 1 MB
#define WS_W3P  (32768u + 4194304u + 1048576u)  // 64 KB
#define WS_OLD_END (32768u + 4194304u + 1048576u + 65536u)
#define WS_W0BX WS_OLD_END                      // 32 KB (optional)
#define WS_W0BY (WS_OLD_END + 32768u)           // 32 KB (optional)
#define WS_NEED (WS_OLD_END + 65536u)

__device__ __forceinline__ u32 pkcvt(float lo, float hi) {
  __hip_bfloat162 h = __float22bfloat162_rn(make_float2(lo, hi));
  u32 u;
  __builtin_memcpy(&u, &h, 4);   // __hip_bfloat162 isn't trivially copyable -> no bit_cast
  return u;
}
__device__ __forceinline__ float tanh_fast(float x) {
  float e = __builtin_amdgcn_exp2f(x * 2.88539008f);   // 2*log2(e)
  return fmaf(-2.0f, __builtin_amdgcn_rcpf(e + 1.0f), 1.0f);
}
// XOR-swizzled LDS addressing: 16B-chunk ^= (row & 7).
__device__ __forceinline__ int swzA(int row, int col) {  // [64][256]
  int ch = col >> 3;
  ch = (ch & ~7) | ((ch ^ row) & 7);
  return (row << 8) + (ch << 3) + (col & 7);
}
__device__ __forceinline__ int swzH(int row, int col) {  // [64][128]
  int ch = col >> 3;
  ch = (ch & ~7) | ((ch ^ row) & 7);
  return (row << 7) + (ch << 3) + (col & 7);
}

// ---------------------------------------------------------------------------
// prep: [0,2048)  base[m][o] = W0a·x0 + b0a + b0b (fp32)
//       [2048,2064)  deinterleave W0b -> W0bx/W0by (if ws has room)
//       [2064,3088)  W1 pack: wave per row, coalesced reads, frag stores
//       [3088,3600)  W2 pack: wave per row
//       [3600,3616)  W3 pack (N padded 3->16 with zeros)
// frag order [m][ks][nt][lane][8]: lane(quad,lrow) holds W[k=ks*32+quad*8+j][n=nt*16+lrow]
// ---------------------------------------------------------------------------
__global__ __launch_bounds__(256) void prep_k(
    const float* __restrict__ x0, const float* __restrict__ W0a,
    const float* __restrict__ b0a, const float* __restrict__ b0b,
    const float* __restrict__ W0b,
    const float* __restrict__ W1, const float* __restrict__ W2,
    const float* __restrict__ W3, float* __restrict__ base,
    bf16_t* __restrict__ W1p, bf16_t* __restrict__ W2p, bf16_t* __restrict__ W3p,
    float* __restrict__ W0bx, float* __restrict__ W0by, int deint)
{
  const int bid = blockIdx.x, tid = threadIdx.x;
  const int w = tid >> 6, L = tid & 63;
  if (bid < 2048) {
    int wid = (bid << 2) + w;
    int m = wid >> 9, o = wid & 511;
    const float* wrow = W0a + ((size_t)(m*S0 + o) << 10);
    float acc = 0.f;
#pragma unroll
    for (int i = 0; i < 4; ++i) {
      f32x4 wv = *(const f32x4*)(wrow + i*256 + L*4);
      f32x4 xv = *(const f32x4*)(x0   + i*256 + L*4);
      acc += wv.x*xv.x + wv.y*xv.y + wv.z*xv.z + wv.w*xv.w;
    }
#pragma unroll
    for (int s = 32; s; s >>= 1) acc += __shfl_xor(acc, s, 64);
    if (L == 0) base[m*S0 + o] = acc + b0a[m*S0 + o] + b0b[m*S0 + o];
  } else if (bid < 2064) {
    if (!deint) return;
    int T = (bid - 2048)*256 + tid;         // [0,4096)
    int m = T >> 8, p = (T & 255) << 1;     // pair index
    f32x4 v = *(const f32x4*)(W0b + ((size_t)m*S0 + p)*2);
    *(f32x2*)(W0bx + m*S0 + p) = (f32x2){v.x, v.z};
    *(f32x2*)(W0by + m*S0 + p) = (f32x2){v.y, v.w};
  } else if (bid < 3088) {
    int wid = (bid - 2064)*4 + w;           // [0,4096)
    int m = wid >> 8, n = wid & 255;
    const float* src = W1 + ((size_t)(m*S1 + n) << 9) + L*8;
    f32x4 a = *(const f32x4*)src;
    f32x4 b = *(const f32x4*)(src + 4);
    u32x4 pu;
    pu[0] = pkcvt(a.x, a.y); pu[1] = pkcvt(a.z, a.w);
    pu[2] = pkcvt(b.x, b.y); pu[3] = pkcvt(b.z, b.w);
    int ks = L >> 2, quad = L & 3, nt = n >> 4, lrow = n & 15;
    *(u32x4*)(W1p + (((size_t)(m*16 + ks)*16 + nt)*64 + quad*16 + lrow)*8) = pu;
  } else if (bid < 3600) {
    int wid = (bid - 3088)*4 + w;           // [0,2048)
    int m = wid >> 7, n = wid & 127;
    const float* src = W2 + ((size_t)(m*S2 + n) << 8) + L*4;
    f32x4 a = *(const f32x4*)src;
    u32x2 pu; pu[0] = pkcvt(a.x, a.y); pu[1] = pkcvt(a.z, a.w);
    int ks = L >> 3, quad = (L >> 1) & 3, half = L & 1, nt = n >> 4, lrow = n & 15;
    *(u32x2*)(W2p + (((size_t)(m*8 + ks)*8 + nt)*64 + quad*16 + lrow)*8 + half*4) = pu;
  } else {
    int T3 = (bid - 3600)*256 + tid;        // [0,4096)
    int l = T3 & 63, ks = (T3 >> 6) & 3, m = T3 >> 8;
    int n = l & 15, k0 = ks*32 + ((l >> 4) & 3)*8;
    bf16x8 v;
    if (n < 3) {
      const float* src = W3 + (size_t)(m*3 + n)*S2 + k0;
      f32x4 a = *(const f32x4*)src;
      f32x4 b = *(const f32x4*)(src + 4);
      v[0]=(bf16_t)a.x; v[1]=(bf16_t)a.y; v[2]=(bf16_t)a.z; v[3]=(bf16_t)a.w;
      v[4]=(bf16_t)b.x; v[5]=(bf16_t)b.y; v[6]=(bf16_t)b.z; v[7]=(bf16_t)b.w;
    } else {
#pragma unroll
      for (int j = 0; j < 8; ++j) v[j] = (bf16_t)0.f;
    }
    *(bf16x8*)(W3p + (size_t)T3*8) = v;
  }
}

// ---------------------------------------------------------------------------
// Fused MLP. One WG = (m = bid>>8, 64-row grid tile). Register h0-gen with
// packed f32 ops + v_cvt_pk_bf16_f32. Swapped MFMA operands -> D = C^T.
// XOR-swizzled LDS. 3 waves/EU: acc footprint (64 f32 + 2x16-reg B frags)
// does NOT fit a 4-wave budget -- launch_bounds(256,4) spilled (R4: 166 MB
// scratch writes). Explicit 1-ahead B prefetch keeps L2 loads in flight.
// ---------------------------------------------------------------------------
__global__ __launch_bounds__(256, 3) void fused_mlp_k(
    const float* __restrict__ base, const float* __restrict__ W0b,
    const float* __restrict__ wxa, const float* __restrict__ wya, int deint,
    const bf16_t* __restrict__ W1p, const bf16_t* __restrict__ W2p,
    const bf16_t* __restrict__ W3p,
    const float* __restrict__ b1, const float* __restrict__ b2,
    const float* __restrict__ b3, float* __restrict__ out)
{
  __shared__ __align__(16) bf16_t sA1[64*256];  // 32 KB; reused as h2 [64][128]

  const int bid  = blockIdx.x;
  const int m    = bid >> 8;
  const int tile = bid & 255;
  const int g0   = tile * 64;

  const int tid  = threadIdx.x;
  const int w    = tid >> 6, L = tid & 63;
  const int quad = L >> 4, lrow = L & 15;

  const float step = 2.0f / 127.0f;
  const float yv  = -1.0f + (float)(tile >> 1) * step;
  const float xv0 = -1.0f + (float)(((tile & 1) << 6) + lrow) * step;

  const float* basep = base + m*S0;
  const float* w0bp  = W0b + (size_t)m*S0*2;
  const float* wxp   = wxa + m*S0;
  const float* wyp   = wya + m*S0;

  const f32x4 zero4 = {0.f, 0.f, 0.f, 0.f};
  f32x4 acc1[4][4];
#pragma unroll
  for (int a = 0; a < 4; ++a)
#pragma unroll
    for (int b = 0; b < 4; ++b) acc1[a][b] = zero4;

  // ---------------- Layer 1: K=512, 16 chunks, barrier-free ----------------
  const bf16_t* bp1 = W1p + (((size_t)(m*16)*16 + w*4)*64 + L)*8;
  const f32x4 yv4 = {yv, yv, yv, yv};

  bf16x8 Bc[4];
#pragma unroll
  for (int n = 0; n < 4; ++n) Bc[n] = *(const bf16x8*)(bp1 + (size_t)n*512);

#pragma unroll 2
  for (int ks = 0; ks < 16; ++ks) {
    const int kk = ks*32 + quad*8;

    bf16x8 Bn[4];
    if (ks < 15) {
#pragma unroll
      for (int n = 0; n < 4; ++n)
        Bn[n] = *(const bf16x8*)(bp1 + (size_t)(ks+1)*8192 + (size_t)n*512);
    }

    f32x4 c0 = *(const f32x4*)(basep + kk);
    f32x4 c1 = *(const f32x4*)(basep + kk + 4);
    f32x4 wx0v, wx1v, wy0v, wy1v;
    if (deint) {
      wx0v = *(const f32x4*)(wxp + kk); wx1v = *(const f32x4*)(wxp + kk + 4);
      wy0v = *(const f32x4*)(wyp + kk); wy1v = *(const f32x4*)(wyp + kk + 4);
    } else {
      f32x4 a = *(const f32x4*)(w0bp + kk*2);
      f32x4 b = *(const f32x4*)(w0bp + kk*2 + 4);
      f32x4 c = *(const f32x4*)(w0bp + kk*2 + 8);
      f32x4 d = *(const f32x4*)(w0bp + kk*2 + 12);
      wx0v = (f32x4){a.x, a.z, b.x, b.z}; wy0v = (f32x4){a.y, a.w, b.y, b.w};
      wx1v = (f32x4){c.x, c.z, d.x, d.z}; wy1v = (f32x4){c.y, c.w, d.y, d.w};
    }
    f32x4 t0 = __builtin_elementwise_fma(wy0v, yv4, c0);
    f32x4 t1 = __builtin_elementwise_fma(wy1v, yv4, c1);

#pragma unroll
    for (int mt = 0; mt < 4; ++mt) {
      const float xr = xv0 + (float)(mt*16)*step;
      const f32x4 xr4 = {xr, xr, xr, xr};
      f32x4 h0 = __builtin_elementwise_max(__builtin_elementwise_fma(wx0v, xr4, t0), zero4);
      f32x4 h1 = __builtin_elementwise_max(__builtin_elementwise_fma(wx1v, xr4, t1), zero4);
      u32x4 au;
      au[0] = pkcvt(h0.x, h0.y); au[1] = pkcvt(h0.z, h0.w);
      au[2] = pkcvt(h1.x, h1.y); au[3] = pkcvt(h1.z, h1.w);
      bf16x8 af;
      __builtin_memcpy(&af, &au, 16);
#pragma unroll
      for (int n = 0; n < 4; ++n)
        acc1[mt][n] = __builtin_amdgcn_mfma_f32_16x16x32_bf16(Bc[n], af, acc1[mt][n], 0, 0, 0);
    }
    if (ks < 15) {
#pragma unroll
      for (int n = 0; n < 4; ++n) Bc[n] = Bn[n];
    }
  }

  // L1 epilogue: +b1, relu, pk-cvt -> swizzled sA1
#pragma unroll
  for (int nb = 0; nb < 4; ++nb) {
    const int col = w*64 + nb*16 + quad*4;
    f32x4 bb = *(const f32x4*)(b1 + m*S1 + col);
#pragma unroll
    for (int mt = 0; mt < 4; ++mt) {
      const int row = mt*16 + lrow;
      f32x4 v = __builtin_elementwise_max(acc1[mt][nb] + bb, zero4);
      u32x2 s; s[0] = pkcvt(v.x, v.y); s[1] = pkcvt(v.z, v.w);
      *(u32x2*)(&sA1[swzA(row, col)]) = s;
    }
  }
  __syncthreads();

  // ---------------- Layer 2: K=256, 8 chunks ----------------
  f32x4 acc2[4][2];
#pragma unroll
  for (int a = 0; a < 4; ++a) { acc2[a][0] = zero4; acc2[a][1] = zero4; }
  const bf16_t* bp2 = W2p + (((size_t)(m*8)*8 + w*2)*64 + L)*8;
#pragma unroll 2
  for (int ks = 0; ks < 8; ++ks) {
    const int k2 = ks*32 + quad*8;
    bf16x8 af[4];
#pragma unroll
    for (int mt = 0; mt < 4; ++mt)
      af[mt] = *(const bf16x8*)(&sA1[swzA(mt*16 + lrow, k2)]);
    bf16x8 b0f = *(const bf16x8*)(bp2 + (size_t)ks*4096);
    bf16x8 b1f = *(const bf16x8*)(bp2 + (size_t)ks*4096 + 512);
#pragma unroll
    for (int mt = 0; mt < 4; ++mt)
      acc2[mt][0] = __builtin_amdgcn_mfma_f32_16x16x32_bf16(b0f, af[mt], acc2[mt][0], 0, 0, 0);
#pragma unroll
    for (int mt = 0; mt < 4; ++mt)
      acc2[mt][1] = __builtin_amdgcn_mfma_f32_16x16x32_bf16(b1f, af[mt], acc2[mt][1], 0, 0, 0);
  }
  __syncthreads();   // all sA1 reads done before aliased h2 writes

  // L2 epilogue: +b2, relu -> swizzled sH2 [64][128]
  bf16_t* sH2 = sA1;
#pragma unroll
  for (int nb = 0; nb < 2; ++nb) {
    const int col = w*32 + nb*16 + quad*4;
    f32x4 bb = *(const f32x4*)(b2 + m*S2 + col);
#pragma unroll
    for (int mt = 0; mt < 4; ++mt) {
      const int row = mt*16 + lrow;
      f32x4 v = __builtin_elementwise_max(acc2[mt][nb] + bb, zero4);
      u32x2 s; s[0] = pkcvt(v.x, v.y); s[1] = pkcvt(v.z, v.w);
      *(u32x2*)(&sH2[swzH(row, col)]) = s;
    }
  }
  __syncthreads();

  // ---------------- Layer 3: K=128, N padded to 16 ----------------
  f32x4 acc3 = zero4;
#pragma unroll
  for (int ks = 0; ks < 4; ++ks) {
    bf16x8 af  = *(const bf16x8*)(&sH2[swzH(w*16 + lrow, ks*32 + quad*8)]);
    bf16x8 bfr = *(const bf16x8*)(W3p + (((size_t)m*4 + ks)*64 + L)*8);
    acc3 = __builtin_amdgcn_mfma_f32_16x16x32_bf16(bfr, af, acc3, 0, 0, 0);
  }
  if (quad == 0) {
    const size_t o = ((size_t)m*GPTS + g0 + w*16 + lrow)*3;
    out[o + 0] = tanh_fast(acc3[0] + b3[m*3 + 0]);
    out[o + 1] = tanh_fast(acc3[1] + b3[m*3 + 1]);
    out[o + 2] = tanh_fast(acc3[2] + b3[m*3 + 2]);
  }
}

// ---------------------------------------------------------------------------
extern "C" void kernel_launch(void* const* d_in, const int* in_sizes, int n_in,
                              void* d_out, int out_size, void* d_ws, size_t ws_size,
                              hipStream_t stream) {
  const float* x0  = (const float*)d_in[0];
  const float* W0a = (const float*)d_in[1];
  const float* b0a = (const float*)d_in[2];
  const float* W0b = (const float*)d_in[3];
  const float* b0b = (const float*)d_in[4];
  const float* W1  = (const float*)d_in[5];
  const float* b1  = (const float*)d_in[6];
  const float* W2  = (const float*)d_in[7];
  const float* b2  = (const float*)d_in[8];
  const float* W3  = (const float*)d_in[9];
  const float* b3  = (const float*)d_in[10];

  char* ws = (char*)d_ws;
  float*  base = (float*)(ws + WS_BASE);
  bf16_t* W1p  = (bf16_t*)(ws + WS_W1P);
  bf16_t* W2p  = (bf16_t*)(ws + WS_W2P);
  bf16_t* W3p  = (bf16_t*)(ws + WS_W3P);
  float*  W0bx = (float*)(ws + WS_W0BX);
  float*  W0by = (float*)(ws + WS_W0BY);
  float*  out  = (float*)d_out;
  int deint = (ws_size >= (size_t)WS_NEED) ? 1 : 0;

  prep_k<<<3616, 256, 0, stream>>>(x0, W0a, b0a, b0b, W0b, W1, W2, W3,
                                   base, W1p, W2p, W3p, W0bx, W0by, deint);
  fused_mlp_k<<<4096, 256, 0, stream>>>(base, W0b, W0bx, W0by, deint,
                                        W1p, W2p, W3p, b1, b2, b3, out);
}

// Round 6
// 230.591 us; speedup vs baseline: 1.4396x; 1.0066x over previous
//
#include <hip/hip_runtime.h>
#include <hip/hip_bf16.h>
#include <cstdint>

typedef __bf16 bf16_t;
typedef bf16_t bf16x8 __attribute__((ext_vector_type(8)));
typedef bf16_t bf16x4 __attribute__((ext_vector_type(4)));
typedef float  f32x4  __attribute__((ext_vector_type(4)));
typedef unsigned int u32;
typedef u32 u32x4 __attribute__((ext_vector_type(4)));
typedef u32 u32x2 __attribute__((ext_vector_type(2)));

#define S0 512
#define S1 256
#define S2 128
#define GPTS 16384

// workspace layout (bytes)
#define WS_BASE 0u
#define WS_W1P  32768u                          // 4 MB
#define WS_W2P  (32768u + 4194304u)             // 1 MB
#define WS_W3P  (32768u + 4194304u + 1048576u)  // 64 KB

__device__ __forceinline__ u32 pkcvt(float lo, float hi) {
  __hip_bfloat162 h = __float22bfloat162_rn(make_float2(lo, hi));
  u32 u;
  __builtin_memcpy(&u, &h, 4);
  return u;
}
__device__ __forceinline__ float tanh_fast(float x) {
  float e = __builtin_amdgcn_exp2f(x * 2.88539008f);   // 2*log2(e)
  return fmaf(-2.0f, __builtin_amdgcn_rcpf(e + 1.0f), 1.0f);
}

// ---------------------------------------------------------------------------
// prep: [0,2048)    base[m][o] = W0a·x0 + b0a + b0b (fp32), one wave/output
//       [2048,3072) W1 pack: wave per row, coalesced 2KB row reads
//       [3072,3584) W2 pack: wave per row
//       [3584,3600) W3 pack (N padded 3->16 with zeros)
// frag order [m][ks][nt][lane][8]: lane(quad,lrow) holds W[k=ks*32+quad*8+j][n=nt*16+lrow]
// ---------------------------------------------------------------------------
__global__ __launch_bounds__(256) void prep_k(
    const float* __restrict__ x0, const float* __restrict__ W0a,
    const float* __restrict__ b0a, const float* __restrict__ b0b,
    const float* __restrict__ W1, const float* __restrict__ W2,
    const float* __restrict__ W3, float* __restrict__ base,
    bf16_t* __restrict__ W1p, bf16_t* __restrict__ W2p, bf16_t* __restrict__ W3p)
{
  const int bid = blockIdx.x, tid = threadIdx.x;
  const int w = tid >> 6, L = tid & 63;
  if (bid < 2048) {
    int wid = (bid << 2) + w;
    int m = wid >> 9, o = wid & 511;
    const float* wrow = W0a + ((size_t)(m*S0 + o) << 10);
    float acc = 0.f;
#pragma unroll
    for (int i = 0; i < 4; ++i) {
      f32x4 wv = *(const f32x4*)(wrow + i*256 + L*4);
      f32x4 xv = *(const f32x4*)(x0   + i*256 + L*4);
      acc += wv.x*xv.x + wv.y*xv.y + wv.z*xv.z + wv.w*xv.w;
    }
#pragma unroll
    for (int s = 32; s; s >>= 1) acc += __shfl_xor(acc, s, 64);
    if (L == 0) base[m*S0 + o] = acc + b0a[m*S0 + o] + b0b[m*S0 + o];
  } else if (bid < 3072) {
    int wid = (bid - 2048)*4 + w;           // [0,4096)
    int m = wid >> 8, n = wid & 255;
    const float* src = W1 + ((size_t)(m*S1 + n) << 9) + L*8;
    f32x4 a = *(const f32x4*)src;
    f32x4 b = *(const f32x4*)(src + 4);
    u32x4 pu;
    pu[0] = pkcvt(a.x, a.y); pu[1] = pkcvt(a.z, a.w);
    pu[2] = pkcvt(b.x, b.y); pu[3] = pkcvt(b.z, b.w);
    int ks = L >> 2, quad = L & 3, nt = n >> 4, lrow = n & 15;
    *(u32x4*)(W1p + (((size_t)(m*16 + ks)*16 + nt)*64 + quad*16 + lrow)*8) = pu;
  } else if (bid < 3584) {
    int wid = (bid - 3072)*4 + w;           // [0,2048)
    int m = wid >> 7, n = wid & 127;
    const float* src = W2 + ((size_t)(m*S2 + n) << 8) + L*4;
    f32x4 a = *(const f32x4*)src;
    u32x2 pu; pu[0] = pkcvt(a.x, a.y); pu[1] = pkcvt(a.z, a.w);
    int ks = L >> 3, quad = (L >> 1) & 3, half = L & 1, nt = n >> 4, lrow = n & 15;
    *(u32x2*)(W2p + (((size_t)(m*8 + ks)*8 + nt)*64 + quad*16 + lrow)*8 + half*4) = pu;
  } else {
    int T3 = (bid - 3584)*256 + tid;        // [0,4096)
    int l = T3 & 63, ks = (T3 >> 6) & 3, m = T3 >> 8;
    int n = l & 15, k0 = ks*32 + ((l >> 4) & 3)*8;
    bf16x8 v;
    if (n < 3) {
      const float* src = W3 + (size_t)(m*3 + n)*S2 + k0;
      f32x4 a = *(const f32x4*)src;
      f32x4 b = *(const f32x4*)(src + 4);
      v[0]=(bf16_t)a.x; v[1]=(bf16_t)a.y; v[2]=(bf16_t)a.z; v[3]=(bf16_t)a.w;
      v[4]=(bf16_t)b.x; v[5]=(bf16_t)b.y; v[6]=(bf16_t)b.z; v[7]=(bf16_t)b.w;
    } else {
#pragma unroll
      for (int j = 0; j < 8; ++j) v[j] = (bf16_t)0.f;
    }
    *(bf16x8*)(W3p + (size_t)T3*8) = v;
  }
}

// ---------------------------------------------------------------------------
// Fused MLP. One WG = (m = bid>>8, 64-row grid tile). Wave mapping: rg=w>>1
// owns rows rg*32..+32 (2 mt), ch=w&1 owns N-half -> A-fragment redundancy 2
// (was 4): halves the L1 h0-gen VALU, halves L2-layer LDS reads. Cost: B-frag
// L2 traffic x2 (L2-resident). Swapped MFMA operands -> D = C^T (thread holds
// 4 contiguous cols -> b64 LDS stores). Padded LDS strides (264/136).
// 3 waves/EU: acc1(64) + 8 B-frags(32) + temps fits 168; (256,4) spills (R4).
// ---------------------------------------------------------------------------
__global__ __launch_bounds__(256, 3) void fused_mlp_k(
    const float* __restrict__ base, const float* __restrict__ W0b,
    const bf16_t* __restrict__ W1p, const bf16_t* __restrict__ W2p,
    const bf16_t* __restrict__ W3p,
    const float* __restrict__ b1, const float* __restrict__ b2,
    const float* __restrict__ b3, float* __restrict__ out)
{
  __shared__ __align__(16) bf16_t sA1[64*264];  // 33792 B; reused as h2 [64][136]

  const int bid  = blockIdx.x;
  const int m    = bid >> 8;            // m-major: weights L2-resident
  const int tile = bid & 255;
  const int g0   = tile * 64;

  const int tid  = threadIdx.x;
  const int w    = tid >> 6, L = tid & 63;
  const int quad = L >> 4, lrow = L & 15;
  const int rg   = w >> 1;              // row-group: rows rg*32 .. rg*32+32
  const int ch   = w & 1;               // N-half

  const float step = 2.0f / 127.0f;
  const float yv  = -1.0f + (float)(tile >> 1) * step;
  const float xv0 = -1.0f + (float)(((tile & 1) << 6) + rg*32 + lrow) * step;  // mt=0

  const float* basep = base + m*S0;
  const float* w0bp  = W0b + (size_t)m*S0*2;

  const f32x4 zero4 = {0.f, 0.f, 0.f, 0.f};
  f32x4 acc1[2][8];
#pragma unroll
  for (int a = 0; a < 2; ++a)
#pragma unroll
    for (int b = 0; b < 8; ++b) acc1[a][b] = zero4;

  // ---------------- Layer 1: K=512, 16 chunks, barrier-free ----------------
  const bf16_t* bp1 = W1p + (((size_t)(m*16)*16 + ch*8)*64 + L)*8;

#pragma unroll 2
  for (int ks = 0; ks < 16; ++ks) {
    const int kk = ks*32 + quad*8;
    bf16x8 Bf[8];
    const bf16_t* bp = bp1 + (size_t)ks*8192;
#pragma unroll
    for (int n = 0; n < 8; ++n) Bf[n] = *(const bf16x8*)(bp + n*512);

    f32x4 cA  = *(const f32x4*)(basep + kk);
    f32x4 cB  = *(const f32x4*)(basep + kk + 4);
    f32x4 wv0 = *(const f32x4*)(w0bp + kk*2);
    f32x4 wv1 = *(const f32x4*)(w0bp + kk*2 + 4);
    f32x4 wv2 = *(const f32x4*)(w0bp + kk*2 + 8);
    f32x4 wv3 = *(const f32x4*)(w0bp + kk*2 + 12);

    float t[8], wx[8];
    t[0] = fmaf(wv0.y, yv, cA.x); wx[0] = wv0.x;
    t[1] = fmaf(wv0.w, yv, cA.y); wx[1] = wv0.z;
    t[2] = fmaf(wv1.y, yv, cA.z); wx[2] = wv1.x;
    t[3] = fmaf(wv1.w, yv, cA.w); wx[3] = wv1.z;
    t[4] = fmaf(wv2.y, yv, cB.x); wx[4] = wv2.x;
    t[5] = fmaf(wv2.w, yv, cB.y); wx[5] = wv2.z;
    t[6] = fmaf(wv3.y, yv, cB.z); wx[6] = wv3.x;
    t[7] = fmaf(wv3.w, yv, cB.w); wx[7] = wv3.z;

#pragma unroll
    for (int mt = 0; mt < 2; ++mt) {
      const float xr = xv0 + (float)(mt*16)*step;
      float h[8];
#pragma unroll
      for (int j = 0; j < 8; ++j)
        h[j] = fmaxf(fmaf(wx[j], xr, t[j]), 0.f);
      u32x4 au;
      au[0] = pkcvt(h[0], h[1]); au[1] = pkcvt(h[2], h[3]);
      au[2] = pkcvt(h[4], h[5]); au[3] = pkcvt(h[6], h[7]);
      bf16x8 af;
      __builtin_memcpy(&af, &au, 16);
#pragma unroll
      for (int n = 0; n < 8; ++n)
        acc1[mt][n] = __builtin_amdgcn_mfma_f32_16x16x32_bf16(Bf[n], af, acc1[mt][n], 0, 0, 0);
    }
  }

  // L1 epilogue: +b1, relu, pk-cvt -> sA1 [64][264], b64 stores
#pragma unroll
  for (int nb = 0; nb < 8; ++nb) {
    const int col = ch*128 + nb*16 + quad*4;
    f32x4 bb = *(const f32x4*)(b1 + m*S1 + col);
#pragma unroll
    for (int mt = 0; mt < 2; ++mt) {
      const int row = rg*32 + mt*16 + lrow;
      f32x4 v = __builtin_elementwise_max(acc1[mt][nb] + bb, zero4);
      u32x2 s; s[0] = pkcvt(v.x, v.y); s[1] = pkcvt(v.z, v.w);
      *(u32x2*)(&sA1[row*264 + col]) = s;
    }
  }
  __syncthreads();

  // ---------------- Layer 2: K=256, 8 chunks ----------------
  f32x4 acc2[2][4];
#pragma unroll
  for (int a = 0; a < 2; ++a)
#pragma unroll
    for (int b = 0; b < 4; ++b) acc2[a][b] = zero4;
  const bf16_t* bp2 = W2p + (((size_t)(m*8)*8 + ch*4)*64 + L)*8;
#pragma unroll 2
  for (int ks = 0; ks < 8; ++ks) {
    const int k2 = ks*32 + quad*8;
    bf16x8 af[2];
#pragma unroll
    for (int mt = 0; mt < 2; ++mt)
      af[mt] = *(const bf16x8*)(&sA1[(rg*32 + mt*16 + lrow)*264 + k2]);
    bf16x8 Bf[4];
#pragma unroll
    for (int n = 0; n < 4; ++n)
      Bf[n] = *(const bf16x8*)(bp2 + (size_t)ks*4096 + n*512);
#pragma unroll
    for (int mt = 0; mt < 2; ++mt)
#pragma unroll
      for (int n = 0; n < 4; ++n)
        acc2[mt][n] = __builtin_amdgcn_mfma_f32_16x16x32_bf16(Bf[n], af[mt], acc2[mt][n], 0, 0, 0);
  }
  __syncthreads();   // all sA1 reads done before aliased h2 writes

  // L2 epilogue: +b2, relu -> sH2 [64][136], b64 stores
  bf16_t* sH2 = sA1;
#pragma unroll
  for (int nb = 0; nb < 4; ++nb) {
    const int col = ch*64 + nb*16 + quad*4;
    f32x4 bb = *(const f32x4*)(b2 + m*S2 + col);
#pragma unroll
    for (int mt = 0; mt < 2; ++mt) {
      const int row = rg*32 + mt*16 + lrow;
      f32x4 v = __builtin_elementwise_max(acc2[mt][nb] + bb, zero4);
      u32x2 s; s[0] = pkcvt(v.x, v.y); s[1] = pkcvt(v.z, v.w);
      *(u32x2*)(&sH2[row*136 + col]) = s;
    }
  }
  __syncthreads();

  // ---------------- Layer 3: K=128, N padded to 16 ----------------
  f32x4 acc3 = zero4;
#pragma unroll
  for (int ks = 0; ks < 4; ++ks) {
    bf16x8 af  = *(const bf16x8*)(&sH2[(w*16 + lrow)*136 + ks*32 + quad*8]);
    bf16x8 bfr = *(const bf16x8*)(W3p + (((size_t)m*4 + ks)*64 + L)*8);
    acc3 = __builtin_amdgcn_mfma_f32_16x16x32_bf16(bfr, af, acc3, 0, 0, 0);
  }
  if (quad == 0) {   // D^T: thread holds channels p=0..2 for grid row w*16+lrow
    const size_t o = ((size_t)m*GPTS + g0 + w*16 + lrow)*3;
    out[o + 0] = tanh_fast(acc3[0] + b3[m*3 + 0]);
    out[o + 1] = tanh_fast(acc3[1] + b3[m*3 + 1]);
    out[o + 2] = tanh_fast(acc3[2] + b3[m*3 + 2]);
  }
}

// ---------------------------------------------------------------------------
extern "C" void kernel_launch(void* const* d_in, const int* in_sizes, int n_in,
                              void* d_out, int out_size, void* d_ws, size_t ws_size,
                              hipStream_t stream) {
  const float* x0  = (const float*)d_in[0];
  const float* W0a = (const float*)d_in[1];
  const float* b0a = (const float*)d_in[2];
  const float* W0b = (const float*)d_in[3];
  const float* b0b = (const float*)d_in[4];
  const float* W1  = (const float*)d_in[5];
  const float* b1  = (const float*)d_in[6];
  const float* W2  = (const float*)d_in[7];
  const float* b2  = (const float*)d_in[8];
  const float* W3  = (const float*)d_in[9];
  const float* b3  = (const float*)d_in[10];

  char* ws = (char*)d_ws;
  float*  base = (float*)(ws + WS_BASE);
  bf16_t* W1p  = (bf16_t*)(ws + WS_W1P);
  bf16_t* W2p  = (bf16_t*)(ws + WS_W2P);
  bf16_t* W3p  = (bf16_t*)(ws + WS_W3P);
  float*  out  = (float*)d_out;

  prep_k<<<3600, 256, 0, stream>>>(x0, W0a, b0a, b0b, W1, W2, W3,
                                   base, W1p, W2p, W3p);
  fused_mlp_k<<<4096, 256, 0, stream>>>(base, W0b, W1p, W2p, W3p, b1, b2, b3, out);
}

// Round 7
// 222.661 us; speedup vs baseline: 1.4908x; 1.0356x over previous
//
#include <hip/hip_runtime.h>
#include <hip/hip_bf16.h>
#include <cstdint>

typedef __bf16 bf16_t;
typedef bf16_t bf16x8 __attribute__((ext_vector_type(8)));
typedef float  f32x4  __attribute__((ext_vector_type(4)));
typedef unsigned int u32;
typedef u32 u32x4 __attribute__((ext_vector_type(4)));
typedef u32 u32x2 __attribute__((ext_vector_type(2)));

#define S0 512
#define S1 256
#define S2 128
#define GPTS 16384

// workspace layout (bytes)
#define WS_BASE 0u
#define WS_W1P  32768u                          // 4 MB
#define WS_W2P  (32768u + 4194304u)             // 1 MB
#define WS_W3P  (32768u + 4194304u + 1048576u)  // 64 KB

__device__ __forceinline__ u32 pkcvt(float lo, float hi) {
  __hip_bfloat162 h = __float22bfloat162_rn(make_float2(lo, hi));
  u32 u;
  __builtin_memcpy(&u, &h, 4);
  return u;
}
__device__ __forceinline__ float tanh_fast(float x) {
  float e = __builtin_amdgcn_exp2f(x * 2.88539008f);   // 2*log2(e)
  return fmaf(-2.0f, __builtin_amdgcn_rcpf(e + 1.0f), 1.0f);
}

// ---------------------------------------------------------------------------
// prep: [0,2048)    base[m][o] = W0a·x0 + b0a + b0b (fp32), one wave/output
//       [2048,3072) W1 pack: wave per row, coalesced 2KB row reads
//       [3072,3584) W2 pack: wave per row
//       [3584,3600) W3 pack (N padded 3->16 with zeros)
// frag order [m][ks][nt][lane][8]: lane(quad,lrow) holds W[k=ks*32+quad*8+j][n=nt*16+lrow]
// ---------------------------------------------------------------------------
__global__ __launch_bounds__(256) void prep_k(
    const float* __restrict__ x0, const float* __restrict__ W0a,
    const float* __restrict__ b0a, const float* __restrict__ b0b,
    const float* __restrict__ W1, const float* __restrict__ W2,
    const float* __restrict__ W3, float* __restrict__ base,
    bf16_t* __restrict__ W1p, bf16_t* __restrict__ W2p, bf16_t* __restrict__ W3p)
{
  const int bid = blockIdx.x, tid = threadIdx.x;
  const int w = tid >> 6, L = tid & 63;
  if (bid < 2048) {
    int wid = (bid << 2) + w;
    int m = wid >> 9, o = wid & 511;
    const float* wrow = W0a + ((size_t)(m*S0 + o) << 10);
    float acc = 0.f;
#pragma unroll
    for (int i = 0; i < 4; ++i) {
      f32x4 wv = *(const f32x4*)(wrow + i*256 + L*4);
      f32x4 xv = *(const f32x4*)(x0   + i*256 + L*4);
      acc += wv.x*xv.x + wv.y*xv.y + wv.z*xv.z + wv.w*xv.w;
    }
#pragma unroll
    for (int s = 32; s; s >>= 1) acc += __shfl_xor(acc, s, 64);
    if (L == 0) base[m*S0 + o] = acc + b0a[m*S0 + o] + b0b[m*S0 + o];
  } else if (bid < 3072) {
    int wid = (bid - 2048)*4 + w;           // [0,4096)
    int m = wid >> 8, n = wid & 255;
    const float* src = W1 + ((size_t)(m*S1 + n) << 9) + L*8;
    f32x4 a = *(const f32x4*)src;
    f32x4 b = *(const f32x4*)(src + 4);
    u32x4 pu;
    pu[0] = pkcvt(a.x, a.y); pu[1] = pkcvt(a.z, a.w);
    pu[2] = pkcvt(b.x, b.y); pu[3] = pkcvt(b.z, b.w);
    int ks = L >> 2, quad = L & 3, nt = n >> 4, lrow = n & 15;
    *(u32x4*)(W1p + (((size_t)(m*16 + ks)*16 + nt)*64 + quad*16 + lrow)*8) = pu;
  } else if (bid < 3584) {
    int wid = (bid - 3072)*4 + w;           // [0,2048)
    int m = wid >> 7, n = wid & 127;
    const float* src = W2 + ((size_t)(m*S2 + n) << 8) + L*4;
    f32x4 a = *(const f32x4*)src;
    u32x2 pu; pu[0] = pkcvt(a.x, a.y); pu[1] = pkcvt(a.z, a.w);
    int ks = L >> 3, quad = (L >> 1) & 3, half = L & 1, nt = n >> 4, lrow = n & 15;
    *(u32x2*)(W2p + (((size_t)(m*8 + ks)*8 + nt)*64 + quad*16 + lrow)*8 + half*4) = pu;
  } else {
    int T3 = (bid - 3584)*256 + tid;        // [0,4096)
    int l = T3 & 63, ks = (T3 >> 6) & 3, m = T3 >> 8;
    int n = l & 15, k0 = ks*32 + ((l >> 4) & 3)*8;
    bf16x8 v;
    if (n < 3) {
      const float* src = W3 + (size_t)(m*3 + n)*S2 + k0;
      f32x4 a = *(const f32x4*)src;
      f32x4 b = *(const f32x4*)(src + 4);
      v[0]=(bf16_t)a.x; v[1]=(bf16_t)a.y; v[2]=(bf16_t)a.z; v[3]=(bf16_t)a.w;
      v[4]=(bf16_t)b.x; v[5]=(bf16_t)b.y; v[6]=(bf16_t)b.z; v[7]=(bf16_t)b.w;
    } else {
#pragma unroll
      for (int j = 0; j < 8; ++j) v[j] = (bf16_t)0.f;
    }
    *(bf16x8*)(W3p + (size_t)T3*8) = v;
  }
}

// ---------------------------------------------------------------------------
// Fused MLP — R2 skeleton (proven 124.5 us) + pk h0-gen/epilogues.
// One WG = (m = bid>>8, 64-row grid tile); m-major -> weights L2-resident.
// Wave w owns N-quarter (4 frags). Each wave redundantly generates its own
// A-frags in registers (barrier-free L1 loop). 1-ahead B prefetch keeps L2
// loads off the critical path. Swapped MFMA operands -> D = C^T (thread holds
// 4 contiguous cols -> b64 LDS stores). Padded LDS strides 264/136.
// (256,3): acc1 64 AGPR + Bc/Bn 32 + temps; (256,4) spills (R4: 166 MB scratch).
// ---------------------------------------------------------------------------
__global__ __launch_bounds__(256, 3) void fused_mlp_k(
    const float* __restrict__ base, const float* __restrict__ W0b,
    const bf16_t* __restrict__ W1p, const bf16_t* __restrict__ W2p,
    const bf16_t* __restrict__ W3p,
    const float* __restrict__ b1, const float* __restrict__ b2,
    const float* __restrict__ b3, float* __restrict__ out)
{
  __shared__ __align__(16) bf16_t sA1[64*264];  // 33792 B; reused as h2 [64][136]

  const int bid  = blockIdx.x;
  const int m    = bid >> 8;
  const int tile = bid & 255;
  const int g0   = tile * 64;

  const int tid  = threadIdx.x;
  const int w    = tid >> 6, L = tid & 63;
  const int quad = L >> 4, lrow = L & 15;

  const float step = 2.0f / 127.0f;
  const float yv  = -1.0f + (float)(tile >> 1) * step;
  const float xv0 = -1.0f + (float)(((tile & 1) << 6) + lrow) * step;  // mt=0 row

  const float* basep = base + m*S0;
  const float* w0bp  = W0b + (size_t)m*S0*2;

  const f32x4 zero4 = {0.f, 0.f, 0.f, 0.f};
  const f32x4 yv4   = {yv, yv, yv, yv};
  f32x4 acc1[4][4];
#pragma unroll
  for (int a = 0; a < 4; ++a)
#pragma unroll
    for (int b = 0; b < 4; ++b) acc1[a][b] = zero4;

  // ---------------- Layer 1: K=512, 16 chunks, barrier-free ----------------
  const bf16_t* bp1 = W1p + (((size_t)(m*16)*16 + w*4)*64 + L)*8;
  bf16x8 Bc[4];
#pragma unroll
  for (int n = 0; n < 4; ++n) Bc[n] = *(const bf16x8*)(bp1 + (size_t)n*512);

#pragma unroll 2
  for (int ks = 0; ks < 16; ++ks) {
    const int kk = ks*32 + quad*8;

    bf16x8 Bn[4];
    if (ks < 15) {
#pragma unroll
      for (int n = 0; n < 4; ++n)
        Bn[n] = *(const bf16x8*)(bp1 + (size_t)(ks+1)*8192 + (size_t)n*512);
    }

    f32x4 c0 = *(const f32x4*)(basep + kk);
    f32x4 c1 = *(const f32x4*)(basep + kk + 4);
    f32x4 a  = *(const f32x4*)(w0bp + kk*2);
    f32x4 b  = *(const f32x4*)(w0bp + kk*2 + 4);
    f32x4 c  = *(const f32x4*)(w0bp + kk*2 + 8);
    f32x4 d  = *(const f32x4*)(w0bp + kk*2 + 12);
    // register deinterleave -> pk-pairable vectors
    f32x4 wx0 = (f32x4){a.x, a.z, b.x, b.z}, wy0 = (f32x4){a.y, a.w, b.y, b.w};
    f32x4 wx1 = (f32x4){c.x, c.z, d.x, d.z}, wy1 = (f32x4){c.y, c.w, d.y, d.w};
    f32x4 t0 = __builtin_elementwise_fma(wy0, yv4, c0);
    f32x4 t1 = __builtin_elementwise_fma(wy1, yv4, c1);

#pragma unroll
    for (int mt = 0; mt < 4; ++mt) {
      const float xr = xv0 + (float)(mt*16)*step;
      const f32x4 xr4 = {xr, xr, xr, xr};
      f32x4 h0 = __builtin_elementwise_max(__builtin_elementwise_fma(wx0, xr4, t0), zero4);
      f32x4 h1 = __builtin_elementwise_max(__builtin_elementwise_fma(wx1, xr4, t1), zero4);
      u32x4 au;
      au[0] = pkcvt(h0.x, h0.y); au[1] = pkcvt(h0.z, h0.w);
      au[2] = pkcvt(h1.x, h1.y); au[3] = pkcvt(h1.z, h1.w);
      bf16x8 af;
      __builtin_memcpy(&af, &au, 16);
#pragma unroll
      for (int n = 0; n < 4; ++n)
        acc1[mt][n] = __builtin_amdgcn_mfma_f32_16x16x32_bf16(Bc[n], af, acc1[mt][n], 0, 0, 0);
    }
    if (ks < 15) {
#pragma unroll
      for (int n = 0; n < 4; ++n) Bc[n] = Bn[n];
    }
  }

  // L1 epilogue: +b1, relu, pk-cvt -> sA1 [64][264], b64 stores
#pragma unroll
  for (int nb = 0; nb < 4; ++nb) {
    const int col = w*64 + nb*16 + quad*4;
    f32x4 bb = *(const f32x4*)(b1 + m*S1 + col);
#pragma unroll
    for (int mt = 0; mt < 4; ++mt) {
      const int row = mt*16 + lrow;
      f32x4 v = __builtin_elementwise_max(acc1[mt][nb] + bb, zero4);
      u32x2 s; s[0] = pkcvt(v.x, v.y); s[1] = pkcvt(v.z, v.w);
      *(u32x2*)(&sA1[row*264 + col]) = s;
    }
  }
  __syncthreads();

  // ---------------- Layer 2: K=256, 8 chunks ----------------
  f32x4 acc2[4][2];
#pragma unroll
  for (int a = 0; a < 4; ++a) { acc2[a][0] = zero4; acc2[a][1] = zero4; }
  const bf16_t* bp2 = W2p + (((size_t)(m*8)*8 + w*2)*64 + L)*8;
#pragma unroll 2
  for (int ks = 0; ks < 8; ++ks) {
    const int k2 = ks*32 + quad*8;
    bf16x8 af[4];
#pragma unroll
    for (int mt = 0; mt < 4; ++mt)
      af[mt] = *(const bf16x8*)(&sA1[(mt*16 + lrow)*264 + k2]);
    bf16x8 b0f = *(const bf16x8*)(bp2 + (size_t)ks*4096);
    bf16x8 b1f = *(const bf16x8*)(bp2 + (size_t)ks*4096 + 512);
#pragma unroll
    for (int mt = 0; mt < 4; ++mt)
      acc2[mt][0] = __builtin_amdgcn_mfma_f32_16x16x32_bf16(b0f, af[mt], acc2[mt][0], 0, 0, 0);
#pragma unroll
    for (int mt = 0; mt < 4; ++mt)
      acc2[mt][1] = __builtin_amdgcn_mfma_f32_16x16x32_bf16(b1f, af[mt], acc2[mt][1], 0, 0, 0);
  }
  __syncthreads();   // all sA1 reads done before aliased h2 writes

  // L2 epilogue: +b2, relu -> sH2 [64][136], b64 stores
  bf16_t* sH2 = sA1;
#pragma unroll
  for (int nb = 0; nb < 2; ++nb) {
    const int col = w*32 + nb*16 + quad*4;
    f32x4 bb = *(const f32x4*)(b2 + m*S2 + col);
#pragma unroll
    for (int mt = 0; mt < 4; ++mt) {
      const int row = mt*16 + lrow;
      f32x4 v = __builtin_elementwise_max(acc2[mt][nb] + bb, zero4);
      u32x2 s; s[0] = pkcvt(v.x, v.y); s[1] = pkcvt(v.z, v.w);
      *(u32x2*)(&sH2[row*136 + col]) = s;
    }
  }
  __syncthreads();

  // ---------------- Layer 3: K=128, N padded to 16 ----------------
  f32x4 acc3 = zero4;
#pragma unroll
  for (int ks = 0; ks < 4; ++ks) {
    bf16x8 af  = *(const bf16x8*)(&sH2[(w*16 + lrow)*136 + ks*32 + quad*8]);
    bf16x8 bfr = *(const bf16x8*)(W3p + (((size_t)m*4 + ks)*64 + L)*8);
    acc3 = __builtin_amdgcn_mfma_f32_16x16x32_bf16(bfr, af, acc3, 0, 0, 0);
  }
  if (quad == 0) {   // D^T: thread holds channels 0..2 for grid row w*16+lrow
    const size_t o = ((size_t)m*GPTS + g0 + w*16 + lrow)*3;
    out[o + 0] = tanh_fast(acc3[0] + b3[m*3 + 0]);
    out[o + 1] = tanh_fast(acc3[1] + b3[m*3 + 1]);
    out[o + 2] = tanh_fast(acc3[2] + b3[m*3 + 2]);
  }
}

// ---------------------------------------------------------------------------
extern "C" void kernel_launch(void* const* d_in, const int* in_sizes, int n_in,
                              void* d_out, int out_size, void* d_ws, size_t ws_size,
                              hipStream_t stream) {
  const float* x0  = (const float*)d_in[0];
  const float* W0a = (const float*)d_in[1];
  const float* b0a = (const float*)d_in[2];
  const float* W0b = (const float*)d_in[3];
  const float* b0b = (const float*)d_in[4];
  const float* W1  = (const float*)d_in[5];
  const float* b1  = (const float*)d_in[6];
  const float* W2  = (const float*)d_in[7];
  const float* b2  = (const float*)d_in[8];
  const float* W3  = (const float*)d_in[9];
  const float* b3  = (const float*)d_in[10];

  char* ws = (char*)d_ws;
  float*  base = (float*)(ws + WS_BASE);
  bf16_t* W1p  = (bf16_t*)(ws + WS_W1P);
  bf16_t* W2p  = (bf16_t*)(ws + WS_W2P);
  bf16_t* W3p  = (bf16_t*)(ws + WS_W3P);
  float*  out  = (float*)d_out;

  prep_k<<<3600, 256, 0, stream>>>(x0, W0a, b0a, b0b, W1, W2, W3,
                                   base, W1p, W2p, W3p);
  fused_mlp_k<<<4096, 256, 0, stream>>>(base, W0b, W1p, W2p, W3p, b1, b2, b3, out);
}